// Round 4
// baseline (928.428 us; speedup 1.0000x reference)
//
#include <hip/hip_runtime.h>

// Scattering_v3_tau: B=500000, C=30, NCON=8, NCC=3, NH=7
// Round 6: issue-throughput-bound at the f32 FLOP ceiling (pk_fma_f32 is
// FLOP-neutral on gfx950: 157.3 TF spec == scalar-FMA full rate).
//  - diffuse MLP -> v_dot2_f32_f16 (2 FMA / 2-cyc slot = 2x f32 rate; f32
//    accumulate, f16 RNE weights, cvt_pkrtz activations) — precision class
//    proven in round 1 (absmax unchanged 0.00390625)
//  - direct MLP stays f32 (features up to ~5e5 overflow f16), but switches to
//    3 pairs + 1 scalar neuron chain (removes the 12.5% zero-pad waste,
//    bit-identical accumulation order)
//  - keeps: 2 elems/thread, cc-folded per-c biases, LOG2E folded, LDS-staged
//    coalesced bf16 stores, dtype-adaptive f32 fallback paths

#define B_SZ 500000
#define C_SZ 30
#define BC   (B_SZ * C_SZ)
#define HBC  (BC / 2)            /* 7,500,000 ; divisible by 30 */
#define EPSF 1e-7f
#define LOG2E 1.4426950408889634f

#if __has_builtin(__builtin_amdgcn_fdot2)
#define HAVE_FDOT2 1
#else
#define HAVE_FDOT2 0
#endif

typedef float f2 __attribute__((ext_vector_type(2)));
typedef __fp16 h2 __attribute__((ext_vector_type(2)));

// ws layout (float/u32 indices; pair segments start even; BEFF* 16B aligned)
enum {
    WD1P  = 0,     // [6][3][2]   direct L1 neuron-pairs (neurons 0..5)
    WD1S  = 36,    // [6]         direct L1 neuron 6
    WDHP  = 42,    // [5][7][3][2]
    WDHS  = 252,   // [5][7]
    BDHP  = 288,   // [5][3][2]
    BDHS  = 318,   // [5]
    WDOP  = 324,   // [7][2][2]   (x LOG2E)
    BDOP  = 352,   // [2][2]      (x LOG2E)
    BEFFD = 360,   // [30][8]     cc-folded L1 biases, direct (slot7=0)
    BEFFF = 600,   // [30][8]     diffuse
    BFH   = 840,   // [5][7]      diffuse hidden biases (f32)
    BFOF  = 876,   // [3]         diffuse out bias (x LOG2E)
    VF16  = 880,   // [7][4] u32  diffuse L1 f16 pairs, natural-t order
    WFH16 = 908,   // [5][7][4] u32
    WFO16 = 1048,  // [3][4] u32  (x LOG2E)
    // f32 diffuse fallback (f32-input mode / no-dot2)
    VF1P  = 1060,  // [6][3][2]   features [t0,t1,t5,t2,s1,0]
    VF1S  = 1096,  // [6]
    VFHP  = 1102,  // [5][7][3][2]
    VFHS  = 1312,  // [5][7]
    BFHP  = 1348,  // [5][3][2]
    BFHS  = 1378,  // [5]
    VFOP  = 1384,  // [7][2][2]   (x LOG2E)
    BFOP  = 1412,  // [2][2]      (x LOG2E)
    WS_FLOATS = 1416
};
#define FLAG_BYTE_OFF 6144

__device__ __forceinline__ float bf2f(unsigned short u) {
    union { unsigned int i; float f; } v;
    v.i = ((unsigned int)u) << 16;
    return v.f;
}

__device__ __forceinline__ unsigned short f2bf(float f) {
    union { float f; unsigned int i; } v;
    v.f = f;
    unsigned int u = v.i;
    unsigned int r = u + 0x7fffu + ((u >> 16) & 1u);  // RNE
    return (unsigned short)(r >> 16);
}

__device__ __forceinline__ float ex2(float x) {
    float r;
    asm("v_exp_f32 %0, %1" : "=v"(r) : "v"(x));
    return r;
}

__device__ __forceinline__ unsigned int pk_bf16(float lo, float hi) {
    unsigned int r;
    asm("v_cvt_pk_bf16_f32 %0, %1, %2" : "=v"(r) : "v"(lo), "v"(hi));
    return r;
}

__device__ __forceinline__ f2 pkfma(f2 a, f2 b, f2 c) {
#if __has_builtin(__builtin_elementwise_fma)
    return __builtin_elementwise_fma(a, b, c);
#else
    f2 r; r.x = fmaf(a.x, b.x, c.x); r.y = fmaf(a.y, b.y, c.y); return r;
#endif
}

__device__ __forceinline__ f2 pkmax0(f2 a) {
    f2 z = {0.0f, 0.0f};
#if __has_builtin(__builtin_elementwise_max)
    return __builtin_elementwise_max(a, z);
#else
    f2 r; r.x = fmaxf(a.x, 0.f); r.y = fmaxf(a.y, 0.f); return r;
#endif
}

__device__ __forceinline__ f2 bc(f2 v, int hl) {
    return hl ? __builtin_shufflevector(v, v, 1, 1)
              : __builtin_shufflevector(v, v, 0, 0);
}

__device__ __forceinline__ h2 uash2(unsigned int u) {
    union { unsigned int u; h2 h; } v; v.u = u; return v.h;
}

// f32 MLP, 2 instances: 6 features (3 pairs), neurons as 3 pairs + 1 scalar.
// Per-neuron accumulation order identical to previous passing rounds.
template <int W1P, int W1S, int WHP, int WHS, int BHP, int BHS, int WOP, int BOP>
__device__ __forceinline__ void mlp_ps2(const float* __restrict__ ws,
                                        const f2 x[2][3], const f2 be[4],
                                        float o[2][3]) {
    const f2* w1 = (const f2*)(ws + W1P);
    f2 hP[2][3]; float hS[2];
#pragma unroll
    for (int h = 0; h < 2; ++h) {
        hP[h][0] = be[0]; hP[h][1] = be[1]; hP[h][2] = be[2];
        hS[h] = be[3].x;
    }
#pragma unroll
    for (int i = 0; i < 6; ++i) {
        f2 xb0 = bc(x[0][i >> 1], i & 1), xb1 = bc(x[1][i >> 1], i & 1);
        float wsc = ws[W1S + i];
#pragma unroll
        for (int p = 0; p < 3; ++p) {
            f2 w = w1[i * 3 + p];
            hP[0][p] = pkfma(xb0, w, hP[0][p]);
            hP[1][p] = pkfma(xb1, w, hP[1][p]);
        }
        hS[0] = fmaf(xb0.x, wsc, hS[0]);
        hS[1] = fmaf(xb1.x, wsc, hS[1]);
    }
#pragma unroll
    for (int h = 0; h < 2; ++h) {
        hP[h][0] = pkmax0(hP[h][0]); hP[h][1] = pkmax0(hP[h][1]);
        hP[h][2] = pkmax0(hP[h][2]); hS[h] = fmaxf(hS[h], 0.f);
    }
    const f2* wh = (const f2*)(ws + WHP);
    const f2* bh = (const f2*)(ws + BHP);
#pragma unroll
    for (int l = 0; l < 5; ++l) {
        f2 nP[2][3]; float nS[2];
#pragma unroll
        for (int p = 0; p < 3; ++p) { f2 b = bh[l * 3 + p]; nP[0][p] = b; nP[1][p] = b; }
        nS[0] = ws[BHS + l]; nS[1] = nS[0];
#pragma unroll
        for (int i = 0; i < 7; ++i) {
            f2 xb0 = (i < 6) ? bc(hP[0][i >> 1], i & 1) : f2{hS[0], hS[0]};
            f2 xb1 = (i < 6) ? bc(hP[1][i >> 1], i & 1) : f2{hS[1], hS[1]};
            float wsc = ws[WHS + l * 7 + i];
#pragma unroll
            for (int p = 0; p < 3; ++p) {
                f2 w = wh[(l * 7 + i) * 3 + p];
                nP[0][p] = pkfma(xb0, w, nP[0][p]);
                nP[1][p] = pkfma(xb1, w, nP[1][p]);
            }
            nS[0] = fmaf(xb0.x, wsc, nS[0]);
            nS[1] = fmaf(xb1.x, wsc, nS[1]);
        }
#pragma unroll
        for (int h = 0; h < 2; ++h) {
            hP[h][0] = pkmax0(nP[h][0]); hP[h][1] = pkmax0(nP[h][1]);
            hP[h][2] = pkmax0(nP[h][2]); hS[h] = fmaxf(nS[h], 0.f);
        }
    }
    const f2* wo = (const f2*)(ws + WOP);
    const f2* bo = (const f2*)(ws + BOP);
    f2 oA[2] = {bo[0], bo[0]}, oB[2] = {bo[1], bo[1]};
#pragma unroll
    for (int i = 0; i < 7; ++i) {
#pragma unroll
        for (int h = 0; h < 2; ++h) {
            f2 xb = (i < 6) ? bc(hP[h][i >> 1], i & 1) : f2{hS[h], hS[h]};
            oA[h] = pkfma(xb, wo[i * 2 + 0], oA[h]);
            oB[h] = pkfma(xb, wo[i * 2 + 1], oB[h]);
        }
    }
#pragma unroll
    for (int h = 0; h < 2; ++h) {
        o[h][0] = oA[h].x; o[h][1] = oA[h].y; o[h][2] = oB[h].x;
    }
}

struct P12 { const void* p[12]; };
// seg order: 0:Wd1(7x9) 1:bd1(7) 2:Wdh(5x7x7) 3:bdh(5x7) 4:Wdo(3x7) 5:bdo(3)
//            6:Wf1(7x8) 7:bf1(7) 8:Wfh(5x7x7) 9:bfh(5x7) 10:Wfo(3x7) 11:bfo(3)

__global__ void prep(P12 ptrs, const unsigned int* __restrict__ tau_raw,
                     float* __restrict__ ws, int* __restrict__ flagp)
{
    __shared__ int sflag;
    int tid = threadIdx.x;
    if (tid < 64) {
        unsigned long long m = __ballot((tau_raw[tid] & 0x8000u) != 0u);
        if (tid == 0) { sflag = (m != 0ull) ? 1 : 0; *flagp = sflag; }
    }
    __syncthreads();
    const int f32m = sflag;

    auto rd = [&](int seg, int idx) -> float {
        if (f32m) return ((const float*)ptrs.p[seg])[idx];
        return bf2f(((const unsigned short*)ptrs.p[seg])[idx]);
    };
    auto ccf = [&](int c, int k) -> float {
        const float C1 = 1.0f / (0.25f * sqrtf(6.28f));
        float ii = (float)c * (1.0f / 29.0f);
        float jj = (float)k * 0.5f;
        float d = (ii - jj) * 4.0f;
        return C1 * expf(-0.5f * d * d);
    };
    auto pk = [&](float a, float b) -> unsigned int {
        union { h2 h; unsigned int u; } v;
        v.h.x = (__fp16)a; v.h.y = (__fp16)b;   // RNE
        return v.u;
    };
    unsigned int* wsu = (unsigned int*)ws;

    // ---- direct f32 pair/scalar segments ----
    for (int i = tid; i < 36; i += 256) {             // WD1P [6][3][2]
        int ii = i / 6, r = i % 6, p = r >> 1, hl = r & 1, j = 2 * p + hl;
        ws[WD1P + i] = rd(0, j * 9 + ii);
    }
    for (int i = tid; i < 6; i += 256) ws[WD1S + i] = rd(0, 6 * 9 + i);
    for (int i = tid; i < 210; i += 256) {            // WDHP [5][7][3][2]
        int l = i / 42, r = i % 42, ii = r / 6, rr = r % 6;
        int p = rr >> 1, hl = rr & 1, j = 2 * p + hl;
        ws[WDHP + i] = rd(2, l * 49 + j * 7 + ii);
    }
    for (int i = tid; i < 35; i += 256) {             // WDHS [5][7]
        int l = i / 7, ii = i % 7;
        ws[WDHS + i] = rd(2, l * 49 + 6 * 7 + ii);
    }
    for (int i = tid; i < 30; i += 256) {             // BDHP [5][3][2]
        int l = i / 6, r = i % 6, p = r >> 1, hl = r & 1, j = 2 * p + hl;
        ws[BDHP + i] = rd(3, l * 7 + j);
    }
    for (int i = tid; i < 5; i += 256) ws[BDHS + i] = rd(3, i * 7 + 6);
    for (int i = tid; i < 28; i += 256) {             // WDOP [7][2][2]
        int ii = i >> 2, p = (i >> 1) & 1, hl = i & 1, k = 2 * p + hl;
        ws[WDOP + i] = (k < 3) ? rd(4, k * 7 + ii) * LOG2E : 0.f;
    }
    for (int i = tid; i < 4; i += 256)
        ws[BDOP + i] = (i < 3) ? rd(5, i) * LOG2E : 0.f;

    // ---- cc-folded L1 biases ----
    for (int i = tid; i < 240; i += 256) {
        int c = i / 8, j = i % 8; float v = 0.f;
        if (j < 7) v = rd(1, j) + rd(0, j * 9 + 6) * ccf(c, 0)
                               + rd(0, j * 9 + 7) * ccf(c, 1)
                               + rd(0, j * 9 + 8) * ccf(c, 2);
        ws[BEFFD + i] = v;
    }
    for (int i = tid; i < 240; i += 256) {
        int c = i / 8, j = i % 8; float v = 0.f;
        if (j < 7) v = rd(7, j) + rd(6, j * 8 + 5) * ccf(c, 0)
                               + rd(6, j * 8 + 6) * ccf(c, 1)
                               + rd(6, j * 8 + 7) * ccf(c, 2);
        ws[BEFFF + i] = v;
    }

    // ---- diffuse f16 (dot2) segments ----
    for (int i = tid; i < 35; i += 256) ws[BFH + i] = rd(9, i);
    for (int i = tid; i < 3; i += 256) ws[BFOF + i] = rd(11, i) * LOG2E;
    // VF16 [7][4]: natural t order, t0..t7 -> Wf1 cols {0,1,3,4,4,2,4,4}
    for (int i = tid; i < 28; i += 256) {
        int j = i / 4, q = i % 4;
        const int cols[8] = {0, 1, 3, 4, 4, 2, 4, 4};
        wsu[VF16 + i] = pk(rd(6, j * 8 + cols[2 * q]), rd(6, j * 8 + cols[2 * q + 1]));
    }
    for (int i = tid; i < 140; i += 256) {            // WFH16 [5*7][4]
        int lj = i / 4, q = i % 4;
        float lo, hi;
        if (q < 3) { lo = rd(8, lj * 7 + 2 * q); hi = rd(8, lj * 7 + 2 * q + 1); }
        else       { lo = rd(8, lj * 7 + 6);     hi = 0.f; }
        wsu[WFH16 + i] = pk(lo, hi);
    }
    for (int i = tid; i < 12; i += 256) {             // WFO16 [3][4] x LOG2E
        int k = i / 4, q = i % 4;
        float lo, hi;
        if (q < 3) { lo = rd(10, k * 7 + 2 * q) * LOG2E; hi = rd(10, k * 7 + 2 * q + 1) * LOG2E; }
        else       { lo = rd(10, k * 7 + 6) * LOG2E;     hi = 0.f; }
        wsu[WFO16 + i] = pk(lo, hi);
    }

    // ---- diffuse f32 fallback segments (features [t0,t1,t5,t2,s1,0] = cols 0..4) ----
    for (int i = tid; i < 36; i += 256) {             // VF1P [6][3][2]
        int ii = i / 6, r = i % 6, p = r >> 1, hl = r & 1, j = 2 * p + hl;
        ws[VF1P + i] = (ii < 5) ? rd(6, j * 8 + ii) : 0.f;
    }
    for (int i = tid; i < 6; i += 256)
        ws[VF1S + i] = (i < 5) ? rd(6, 6 * 8 + i) : 0.f;
    for (int i = tid; i < 210; i += 256) {            // VFHP [5][7][3][2]
        int l = i / 42, r = i % 42, ii = r / 6, rr = r % 6;
        int p = rr >> 1, hl = rr & 1, j = 2 * p + hl;
        ws[VFHP + i] = rd(8, l * 49 + j * 7 + ii);
    }
    for (int i = tid; i < 35; i += 256) {             // VFHS [5][7]
        int l = i / 7, ii = i % 7;
        ws[VFHS + i] = rd(8, l * 49 + 6 * 7 + ii);
    }
    for (int i = tid; i < 30; i += 256) {             // BFHP [5][3][2]
        int l = i / 6, r = i % 6, p = r >> 1, hl = r & 1, j = 2 * p + hl;
        ws[BFHP + i] = rd(9, l * 7 + j);
    }
    for (int i = tid; i < 5; i += 256) ws[BFHS + i] = rd(9, i * 7 + 6);
    for (int i = tid; i < 28; i += 256) {             // VFOP [7][2][2] x LOG2E
        int ii = i >> 2, p = (i >> 1) & 1, hl = i & 1, k = 2 * p + hl;
        ws[VFOP + i] = (k < 3) ? rd(10, k * 7 + ii) * LOG2E : 0.f;
    }
    for (int i = tid; i < 4; i += 256)
        ws[BFOP + i] = (i < 3) ? rd(11, i) * LOG2E : 0.f;
}

__global__ __launch_bounds__(256, 4) void scatter_main(
    const void* __restrict__ tau_p,    // (B,C,8) bf16 or f32
    const void* __restrict__ mu_dir_p, // (B,1)
    const void* __restrict__ mu_dif_p, // (B,1)
    const float* __restrict__ ws,
    const int* __restrict__ flag,      // 1 = f32, 0 = bf16
    void* __restrict__ out_p)          // out: [BC | BC | 3BC | 3BC]
{
    __shared__ unsigned short sm[2][2048];  // 8 KiB output staging (2 halves)

    int tid = threadIdx.x;
    int eb0 = blockIdx.x * 256;
    int e0 = eb0 + tid;                  // [0, HBC)
    bool act = (e0 < HBC);
    int eL = act ? e0 : (HBC - 1);
    int b0 = eL / C_SZ;
    int c  = eL - b0 * C_SZ;
    int b1 = b0 + (HBC / C_SZ);          // +250000
    bool tail = (eb0 + 256 > HBC);       // block-uniform

    int is_f32 = *flag;                  // grid-uniform

    // ---------------- loads, both halves ----------------
    float T[2][8], MUD[2], MUF[2];
    if (is_f32) {
        const float4* tf = (const float4*)tau_p;
#pragma unroll
        for (int h = 0; h < 2; ++h) {
            int ee = eL + h * HBC;
            float4 a = tf[2 * ee], bq = tf[2 * ee + 1];
            T[h][0] = a.x;  T[h][1] = a.y;  T[h][2] = a.z;  T[h][3] = a.w;
            T[h][4] = bq.x; T[h][5] = bq.y; T[h][6] = bq.z; T[h][7] = bq.w;
        }
        MUD[0] = ((const float*)mu_dir_p)[b0];
        MUD[1] = ((const float*)mu_dir_p)[b1];
        MUF[0] = ((const float*)mu_dif_p)[b0];
        MUF[1] = ((const float*)mu_dif_p)[b1];
    } else {
        const uint4* tu = (const uint4*)tau_p;
#pragma unroll
        for (int h = 0; h < 2; ++h) {
            uint4 t = tu[eL + h * HBC];
            T[h][0] = bf2f((unsigned short)(t.x & 0xffffu));
            T[h][1] = bf2f((unsigned short)(t.x >> 16));
            T[h][2] = bf2f((unsigned short)(t.y & 0xffffu));
            T[h][3] = bf2f((unsigned short)(t.y >> 16));
            T[h][4] = bf2f((unsigned short)(t.z & 0xffffu));
            T[h][5] = bf2f((unsigned short)(t.z >> 16));
            T[h][6] = bf2f((unsigned short)(t.w & 0xffffu));
            T[h][7] = bf2f((unsigned short)(t.w >> 16));
        }
        MUD[0] = bf2f(((const unsigned short*)mu_dir_p)[b0]);
        MUD[1] = bf2f(((const unsigned short*)mu_dir_p)[b1]);
        MUF[0] = bf2f(((const unsigned short*)mu_dif_p)[b0]);
        MUF[1] = bf2f(((const unsigned short*)mu_dif_p)[b1]);
    }

    // shared per-c cc-folded L1 bias pairs
    f2 bed[4], bef[4];
    {
        const float4* q = (const float4*)(ws + BEFFD) + 2 * c;
        float4 qa = q[0], qb = q[1];
        bed[0] = f2{qa.x, qa.y}; bed[1] = f2{qa.z, qa.w};
        bed[2] = f2{qb.x, qb.y}; bed[3] = f2{qb.z, qb.w};
        const float4* r = (const float4*)(ws + BEFFF) + 2 * c;
        float4 ra = r[0], rb = r[1];
        bef[0] = f2{ra.x, ra.y}; bef[1] = f2{ra.z, ra.w};
        bef[2] = f2{rb.x, rb.y}; bef[3] = f2{rb.z, rb.w};
    }

    // ---------------- per-half prologue ----------------
    float tdir[2], tdif[2], s1v[2];
    f2 xd[2][3];
#pragma unroll
    for (int h = 0; h < 2; ++h) {
        float rcp_d = __builtin_amdgcn_rcpf(MUD[h] + EPSF);
        float rcp_f = __builtin_amdgcn_rcpf(MUF[h] + EPSF);
        float tt = ((T[h][0] + T[h][1]) + (T[h][2] + T[h][3]))
                 + ((T[h][4] + T[h][5]) + (T[h][6] + T[h][7]));
        float ttl = tt * LOG2E;
        tdir[h] = ex2(-ttl * rcp_d);
        tdif[h] = ex2(-ttl * rcp_f);
        s1v[h] = (T[h][3] + T[h][4]) + (T[h][6] + T[h][7]);
        xd[h][0] = f2{T[h][0] * rcp_d, T[h][1] * rcp_d};
        xd[h][1] = f2{T[h][5] * rcp_d, T[h][2] * rcp_d};
        xd[h][2] = f2{s1v[h] * rcp_d, MUD[h]};
    }

    // ---------------- direct MLP (f32, pairs+scalar) ----------------
    float od[2][3];
    mlp_ps2<WD1P, WD1S, WDHP, WDHS, BDHP, BDHS, WDOP, BDOP>(ws, xd, bed, od);

    // ---------------- diffuse MLP ----------------
    float of_[2][3];
#if HAVE_FDOT2
    if (!is_f32) {
        const unsigned int* wsu = (const unsigned int*)ws;
        h2 xq[2][4];
#pragma unroll
        for (int h = 0; h < 2; ++h) {   // bf16-origin values: pkrtz exact
            xq[h][0] = __builtin_amdgcn_cvt_pkrtz(T[h][0], T[h][1]);
            xq[h][1] = __builtin_amdgcn_cvt_pkrtz(T[h][2], T[h][3]);
            xq[h][2] = __builtin_amdgcn_cvt_pkrtz(T[h][4], T[h][5]);
            xq[h][3] = __builtin_amdgcn_cvt_pkrtz(T[h][6], T[h][7]);
        }
        float hf[2][7];
#pragma unroll
        for (int j = 0; j < 7; ++j) {   // L1: 8 raw-t features (exact in f16)
            float b = (j < 6) ? ((j & 1) ? bef[j >> 1].y : bef[j >> 1].x) : bef[3].x;
            float a0 = b, a1 = b;
#pragma unroll
            for (int q = 0; q < 4; ++q) {
                h2 w = uash2(wsu[VF16 + j * 4 + q]);
                a0 = __builtin_amdgcn_fdot2(xq[0][q], w, a0, false);
                a1 = __builtin_amdgcn_fdot2(xq[1][q], w, a1, false);
            }
            hf[0][j] = fmaxf(a0, 0.f); hf[1][j] = fmaxf(a1, 0.f);
        }
#pragma unroll
        for (int l = 0; l < 5; ++l) {
            h2 hp[2][4];
#pragma unroll
            for (int h = 0; h < 2; ++h) {
                hp[h][0] = __builtin_amdgcn_cvt_pkrtz(hf[h][0], hf[h][1]);
                hp[h][1] = __builtin_amdgcn_cvt_pkrtz(hf[h][2], hf[h][3]);
                hp[h][2] = __builtin_amdgcn_cvt_pkrtz(hf[h][4], hf[h][5]);
                hp[h][3] = __builtin_amdgcn_cvt_pkrtz(hf[h][6], 0.f);
            }
#pragma unroll
            for (int j = 0; j < 7; ++j) {
                float b = ws[BFH + l * 7 + j];
                float a0 = b, a1 = b;
#pragma unroll
                for (int q = 0; q < 4; ++q) {
                    h2 w = uash2(wsu[WFH16 + (l * 7 + j) * 4 + q]);
                    a0 = __builtin_amdgcn_fdot2(hp[0][q], w, a0, false);
                    a1 = __builtin_amdgcn_fdot2(hp[1][q], w, a1, false);
                }
                hf[0][j] = fmaxf(a0, 0.f); hf[1][j] = fmaxf(a1, 0.f);
            }
        }
        h2 op[2][4];
#pragma unroll
        for (int h = 0; h < 2; ++h) {
            op[h][0] = __builtin_amdgcn_cvt_pkrtz(hf[h][0], hf[h][1]);
            op[h][1] = __builtin_amdgcn_cvt_pkrtz(hf[h][2], hf[h][3]);
            op[h][2] = __builtin_amdgcn_cvt_pkrtz(hf[h][4], hf[h][5]);
            op[h][3] = __builtin_amdgcn_cvt_pkrtz(hf[h][6], 0.f);
        }
#pragma unroll
        for (int k = 0; k < 3; ++k) {   // out weights pre-scaled by LOG2E
            float b = ws[BFOF + k];
            float a0 = b, a1 = b;
#pragma unroll
            for (int q = 0; q < 4; ++q) {
                h2 w = uash2(wsu[WFO16 + k * 4 + q]);
                a0 = __builtin_amdgcn_fdot2(op[0][q], w, a0, false);
                a1 = __builtin_amdgcn_fdot2(op[1][q], w, a1, false);
            }
            of_[0][k] = a0; of_[1][k] = a1;
        }
    } else
#endif
    {
        f2 xf[2][3];
#pragma unroll
        for (int h = 0; h < 2; ++h) {
            xf[h][0] = f2{T[h][0], T[h][1]};
            xf[h][1] = f2{T[h][5], T[h][2]};
            xf[h][2] = f2{s1v[h], 0.0f};
        }
        mlp_ps2<VF1P, VF1S, VFHP, VFHS, BFHP, BFHS, VFOP, BFOP>(ws, xf, bef, of_);
    }

    // ---------------- softmax (logits pre-scaled by LOG2E) ----------------
    float D0[2], D1[2], D2[2], F0[2], F1[2], F2[2];
#pragma unroll
    for (int h = 0; h < 2; ++h) {
        float md = fmaxf(fmaxf(od[h][0], od[h][1]), od[h][2]);
        float d0 = ex2(od[h][0] - md), d1 = ex2(od[h][1] - md), d2 = ex2(od[h][2] - md);
        float rdd = __builtin_amdgcn_rcpf(d0 + d1 + d2);
        D0[h] = d0 * rdd; D1[h] = d1 * rdd; D2[h] = d2 * rdd;
        float mf = fmaxf(fmaxf(of_[h][0], of_[h][1]), of_[h][2]);
        float f0 = ex2(of_[h][0] - mf), f1 = ex2(of_[h][1] - mf), f2v = ex2(of_[h][2] - mf);
        float rff = __builtin_amdgcn_rcpf(f0 + f1 + f2v);
        F0[h] = f0 * rff; F1[h] = f1 * rff; F2[h] = f2v * rff;
    }

    // ---------------- stores ----------------
    if (!is_f32 && !tail) {
#pragma unroll
        for (int h = 0; h < 2; ++h) {
            unsigned int P1 = pk_bf16(tdir[h], tdif[h]);
            unsigned int P2 = pk_bf16(D0[h], D1[h]);
            unsigned int P3 = pk_bf16(D2[h], F0[h]);
            unsigned int P4 = pk_bf16(F1[h], F2[h]);
            sm[h][tid]       = (unsigned short)P1;
            sm[h][256 + tid] = (unsigned short)(P1 >> 16);
            int db = 512 + 3 * tid;
            sm[h][db + 0] = (unsigned short)P2;
            sm[h][db + 1] = (unsigned short)(P2 >> 16);
            sm[h][db + 2] = (unsigned short)P3;
            int fb = 1280 + 3 * tid;
            sm[h][fb + 0] = (unsigned short)(P3 >> 16);
            sm[h][fb + 1] = (unsigned short)P4;
            sm[h][fb + 2] = (unsigned short)(P4 >> 16);
        }
        __syncthreads();
#pragma unroll
        for (int h = 0; h < 2; ++h) {
            uint4 v = ((const uint4*)sm[h])[tid];
            unsigned int E = (h ? (unsigned int)HBC : 0u) + (unsigned int)eb0;
            unsigned int goff;
            if (tid < 32)        goff = 2u * E + 16u * tid;
            else if (tid < 64)   goff = 2u * ((unsigned int)BC + E) + 16u * (tid - 32);
            else if (tid < 160)  goff = 4u * (unsigned int)BC + 6u * E + 16u * (tid - 64);
            else                 goff = 10u * (unsigned int)BC + 6u * E + 16u * (tid - 160);
            *(uint4*)((char*)out_p + goff) = v;
        }
    } else if (!is_f32) {
        if (act) {
            unsigned short* out = (unsigned short*)out_p;
#pragma unroll
            for (int h = 0; h < 2; ++h) {
                int e = e0 + h * HBC;
                int odb = 2 * BC + 3 * e;
                int ofb = 5 * BC + 3 * e;
                out[e]       = f2bf(tdir[h]);
                out[BC + e]  = f2bf(tdif[h]);
                out[odb + 0] = f2bf(D0[h]);
                out[odb + 1] = f2bf(D1[h]);
                out[odb + 2] = f2bf(D2[h]);
                out[ofb + 0] = f2bf(F0[h]);
                out[ofb + 1] = f2bf(F1[h]);
                out[ofb + 2] = f2bf(F2[h]);
            }
        }
    } else {
        if (act) {
            float* out = (float*)out_p;
#pragma unroll
            for (int h = 0; h < 2; ++h) {
                int e = e0 + h * HBC;
                int odb = 2 * BC + 3 * e;
                int ofb = 5 * BC + 3 * e;
                out[e] = tdir[h];
                out[BC + e] = tdif[h];
                out[odb + 0] = D0[h]; out[odb + 1] = D1[h]; out[odb + 2] = D2[h];
                out[ofb + 0] = F0[h]; out[ofb + 1] = F1[h]; out[ofb + 2] = F2[h];
            }
        }
    }
}

extern "C" void kernel_launch(void* const* d_in, const int* in_sizes, int n_in,
                              void* d_out, int out_size, void* d_ws, size_t ws_size,
                              hipStream_t stream) {
    float* ws = (float*)d_ws;
    int* flag = (int*)((char*)d_ws + FLAG_BYTE_OFF);

    P12 p;
    for (int i = 0; i < 12; ++i) p.p[i] = d_in[3 + i];
    prep<<<1, 256, 0, stream>>>(p, (const unsigned int*)d_in[0], ws, flag);

    int nblk = (HBC + 255) / 256;
    scatter_main<<<nblk, 256, 0, stream>>>(
        d_in[0], d_in[1], d_in[2], ws, flag, d_out);
}

// Round 5
// 831.539 us; speedup vs baseline: 1.1165x; 1.1165x over previous
//
#include <hip/hip_runtime.h>

// Scattering_v3_tau: B=500000, C=30, NCON=8, NCC=3, NH=7
// Round 7: revert to round-3 structure (best: dur 839, scatter ~290) after the
// fdot2 experiment regressed (codegen: scattered mixed-type weight segments broke
// s_load batching; dot2 numerics were fine - absmax identical - but 405 us).
// Trims on top of r3 (all keep per-neuron f32 accumulation order):
//  - diffuse L1 zero-column (i=5) skipped: -8 pk_fma/thread
//  - output neuron 2 via scalar fma chain (2cyc) instead of half-wasted pair (4cyc)
//  - out-weight layout: contiguous pair stream + scalar stream (s_load friendly)
// Keeps: 2 elems/thread, packed f32 everywhere, cc-folded per-c biases, LOG2E
// folded, LDS-staged coalesced bf16 stores, dtype-adaptive single compute path.

#define B_SZ 500000
#define C_SZ 30
#define BC   (B_SZ * C_SZ)
#define HBC  (BC / 2)            /* 7,500,000 ; divisible by 30 */
#define EPSF 1e-7f
#define LOG2E 1.4426950408889634f

typedef float f2 __attribute__((ext_vector_type(2)));

// ws layout (float indices; pair segments even -> 8B aligned; BEFF* 16B aligned)
enum {
    WD1P  = 0,     // [6][4][2]   direct L1 pairs, features [t0r,t1r,t5r,t2r,s1r,mu]
    WF1P  = 48,    // [6][4][2]   diffuse L1 pairs, features [t0,t1,t5,t2,s1,-] (col5=0, unused)
    WDHP  = 96,    // [5][7][4][2]
    WFHP  = 376,   // [5][7][4][2]
    BDHP  = 656,   // [5][4][2]
    BFHP  = 696,   // [5][4][2]
    WDOP  = 736,   // [7][2]      out pairs {k0,k1} (x LOG2E)
    WDOS  = 750,   // [7]         out scalar k2 (x LOG2E)
    BDOP  = 758,   // [2]         {b0,b1} (x LOG2E)
    BDOS  = 760,   // [1]         b2 (x LOG2E)
    WFOP  = 762,   // [7][2]      (x LOG2E)
    WFOS  = 776,   // [7]
    BFOP  = 784,   // [2]
    BFOS  = 786,   // [1]
    BEFFD = 792,   // [30][8]     cc-folded L1 biases, direct (slot7=0)
    BEFFF = 1032,  // [30][8]     diffuse
    WS_FLOATS = 1272
};
#define FLAG_BYTE_OFF 6144

__device__ __forceinline__ float bf2f(unsigned short u) {
    union { unsigned int i; float f; } v;
    v.i = ((unsigned int)u) << 16;
    return v.f;
}

__device__ __forceinline__ unsigned short f2bf(float f) {
    union { float f; unsigned int i; } v;
    v.f = f;
    unsigned int u = v.i;
    unsigned int r = u + 0x7fffu + ((u >> 16) & 1u);  // RNE
    return (unsigned short)(r >> 16);
}

__device__ __forceinline__ float ex2(float x) {
    float r;
    asm("v_exp_f32 %0, %1" : "=v"(r) : "v"(x));
    return r;
}

__device__ __forceinline__ unsigned int pk_bf16(float lo, float hi) {
    unsigned int r;
    asm("v_cvt_pk_bf16_f32 %0, %1, %2" : "=v"(r) : "v"(lo), "v"(hi));
    return r;
}

__device__ __forceinline__ f2 pkfma(f2 a, f2 b, f2 c) {
#if __has_builtin(__builtin_elementwise_fma)
    return __builtin_elementwise_fma(a, b, c);
#else
    f2 r; r.x = fmaf(a.x, b.x, c.x); r.y = fmaf(a.y, b.y, c.y); return r;
#endif
}

__device__ __forceinline__ f2 pkmax0(f2 a) {
    f2 z = {0.0f, 0.0f};
#if __has_builtin(__builtin_elementwise_max)
    return __builtin_elementwise_max(a, z);
#else
    f2 r; r.x = fmaxf(a.x, 0.f); r.y = fmaxf(a.y, 0.f); return r;
#endif
}

__device__ __forceinline__ f2 bc(f2 v, int hl) {
    return hl ? __builtin_shufflevector(v, v, 1, 1)
              : __builtin_shufflevector(v, v, 0, 0);
}

__device__ __forceinline__ float half_of(f2 v, int hl) {
    return hl ? v.y : v.x;
}

struct P12 { const void* p[12]; };
// seg order: 0:Wd1(7x9) 1:bd1(7) 2:Wdh(5x7x7) 3:bdh(5x7) 4:Wdo(3x7) 5:bdo(3)
//            6:Wf1(7x8) 7:bf1(7) 8:Wfh(5x7x7) 9:bfh(5x7) 10:Wfo(3x7) 11:bfo(3)

__global__ void prep(P12 ptrs, const unsigned int* __restrict__ tau_raw,
                     float* __restrict__ ws, int* __restrict__ flagp)
{
    __shared__ int sflag;
    int tid = threadIdx.x;
    if (tid < 64) {
        unsigned long long m = __ballot((tau_raw[tid] & 0x8000u) != 0u);
        if (tid == 0) { sflag = (m != 0ull) ? 1 : 0; *flagp = sflag; }
    }
    __syncthreads();
    const int f32m = sflag;

    auto rd = [&](int seg, int idx) -> float {
        if (f32m) return ((const float*)ptrs.p[seg])[idx];
        return bf2f(((const unsigned short*)ptrs.p[seg])[idx]);
    };
    auto ccf = [&](int c, int k) -> float {
        const float C1 = 1.0f / (0.25f * sqrtf(6.28f));
        float ii = (float)c * (1.0f / 29.0f);
        float jj = (float)k * 0.5f;
        float d = (ii - jj) * 4.0f;
        return C1 * expf(-0.5f * d * d);
    };

    // direct L1 packed [6][4][2]: feature i <-> Wd1 col i (i=0..5)
    for (int i = tid; i < 48; i += 256) {
        int ii = i >> 3, p = (i >> 1) & 3, hl = i & 1, j = 2 * p + hl;
        ws[WD1P + i] = (j < 7) ? rd(0, j * 9 + ii) : 0.f;
    }
    // diffuse L1 packed [6][4][2]: feature i <-> Wf1 col i (i=0..4), slot5 = 0
    for (int i = tid; i < 48; i += 256) {
        int ii = i >> 3, p = (i >> 1) & 3, hl = i & 1, j = 2 * p + hl;
        ws[WF1P + i] = (j < 7 && ii < 5) ? rd(6, j * 8 + ii) : 0.f;
    }
    // hidden packed [5][7][4][2]
    for (int i = tid; i < 280; i += 256) {
        int l = i / 56, r = i % 56;
        int ii = r >> 3, p = (r >> 1) & 3, hl = r & 1, j = 2 * p + hl;
        ws[WDHP + i] = (j < 7) ? rd(2, l * 49 + j * 7 + ii) : 0.f;
        ws[WFHP + i] = (j < 7) ? rd(8, l * 49 + j * 7 + ii) : 0.f;
    }
    // hidden bias pairs [5][4][2]
    for (int i = tid; i < 40; i += 256) {
        int l = i / 8, p = (i >> 1) & 3, hl = i & 1, j = 2 * p + hl;
        ws[BDHP + i] = (j < 7) ? rd(3, l * 7 + j) : 0.f;
        ws[BFHP + i] = (j < 7) ? rd(9, l * 7 + j) : 0.f;
    }
    // out pairs [7][2] (k=0,1) x LOG2E
    for (int i = tid; i < 14; i += 256) {
        int ii = i >> 1, k = i & 1;
        ws[WDOP + i] = rd(4, k * 7 + ii) * LOG2E;
        ws[WFOP + i] = rd(10, k * 7 + ii) * LOG2E;
    }
    // out scalar [7] (k=2) x LOG2E
    for (int i = tid; i < 7; i += 256) {
        ws[WDOS + i] = rd(4, 14 + i) * LOG2E;
        ws[WFOS + i] = rd(10, 14 + i) * LOG2E;
    }
    for (int i = tid; i < 2; i += 256) {
        ws[BDOP + i] = rd(5, i) * LOG2E;
        ws[BFOP + i] = rd(11, i) * LOG2E;
    }
    if (tid == 0) {
        ws[BDOS] = rd(5, 2) * LOG2E;
        ws[BFOS] = rd(11, 2) * LOG2E;
    }
    // beff_d[c][j] = bd1[j] + sum_k Wd1[j,6+k]*cc[c][k]
    for (int i = tid; i < 240; i += 256) {
        int c = i / 8, j = i % 8; float v = 0.f;
        if (j < 7) v = rd(1, j) + rd(0, j * 9 + 6) * ccf(c, 0)
                               + rd(0, j * 9 + 7) * ccf(c, 1)
                               + rd(0, j * 9 + 8) * ccf(c, 2);
        ws[BEFFD + i] = v;
    }
    // beff_f[c][j] = bf1[j] + sum_k Wf1[j,5+k]*cc[c][k]
    for (int i = tid; i < 240; i += 256) {
        int c = i / 8, j = i % 8; float v = 0.f;
        if (j < 7) v = rd(7, j) + rd(6, j * 8 + 5) * ccf(c, 0)
                               + rd(6, j * 8 + 6) * ccf(c, 1)
                               + rd(6, j * 8 + 7) * ccf(c, 2);
        ws[BEFFF + i] = v;
    }
}

__global__ __launch_bounds__(256, 4) void scatter_main(
    const void* __restrict__ tau_p,    // (B,C,8) bf16 or f32
    const void* __restrict__ mu_dir_p, // (B,1)
    const void* __restrict__ mu_dif_p, // (B,1)
    const float* __restrict__ ws,
    const int* __restrict__ flag,      // 1 = f32, 0 = bf16
    void* __restrict__ out_p)          // out: [BC | BC | 3BC | 3BC]
{
    __shared__ unsigned short sm[2][2048];  // 8 KiB output staging (2 halves)

    int tid = threadIdx.x;
    int eb0 = blockIdx.x * 256;
    int e0 = eb0 + tid;                  // [0, HBC)
    bool act = (e0 < HBC);
    int eL = act ? e0 : (HBC - 1);
    int b0 = eL / C_SZ;
    int c  = eL - b0 * C_SZ;
    int b1 = b0 + (HBC / C_SZ);          // +250000
    bool tail = (eb0 + 256 > HBC);       // block-uniform

    int is_f32 = *flag;                  // grid-uniform

    // ---------------- loads, both halves ----------------
    float T[2][8], MUD[2], MUF[2];
    if (is_f32) {
        const float4* tf = (const float4*)tau_p;
#pragma unroll
        for (int h = 0; h < 2; ++h) {
            int ee = eL + h * HBC;
            float4 a = tf[2 * ee], bq = tf[2 * ee + 1];
            T[h][0] = a.x;  T[h][1] = a.y;  T[h][2] = a.z;  T[h][3] = a.w;
            T[h][4] = bq.x; T[h][5] = bq.y; T[h][6] = bq.z; T[h][7] = bq.w;
        }
        MUD[0] = ((const float*)mu_dir_p)[b0];
        MUD[1] = ((const float*)mu_dir_p)[b1];
        MUF[0] = ((const float*)mu_dif_p)[b0];
        MUF[1] = ((const float*)mu_dif_p)[b1];
    } else {
        const uint4* tu = (const uint4*)tau_p;
#pragma unroll
        for (int h = 0; h < 2; ++h) {
            uint4 t = tu[eL + h * HBC];
            T[h][0] = bf2f((unsigned short)(t.x & 0xffffu));
            T[h][1] = bf2f((unsigned short)(t.x >> 16));
            T[h][2] = bf2f((unsigned short)(t.y & 0xffffu));
            T[h][3] = bf2f((unsigned short)(t.y >> 16));
            T[h][4] = bf2f((unsigned short)(t.z & 0xffffu));
            T[h][5] = bf2f((unsigned short)(t.z >> 16));
            T[h][6] = bf2f((unsigned short)(t.w & 0xffffu));
            T[h][7] = bf2f((unsigned short)(t.w >> 16));
        }
        MUD[0] = bf2f(((const unsigned short*)mu_dir_p)[b0]);
        MUD[1] = bf2f(((const unsigned short*)mu_dir_p)[b1]);
        MUF[0] = bf2f(((const unsigned short*)mu_dif_p)[b0]);
        MUF[1] = bf2f(((const unsigned short*)mu_dif_p)[b1]);
    }

    // shared per-c cc-folded L1 bias pairs
    f2 bed[4], bef[4];
    {
        const float4* q = (const float4*)(ws + BEFFD) + 2 * c;
        float4 qa = q[0], qb = q[1];
        bed[0] = f2{qa.x, qa.y}; bed[1] = f2{qa.z, qa.w};
        bed[2] = f2{qb.x, qb.y}; bed[3] = f2{qb.z, qb.w};
        const float4* r = (const float4*)(ws + BEFFF) + 2 * c;
        float4 ra = r[0], rb = r[1];
        bef[0] = f2{ra.x, ra.y}; bef[1] = f2{ra.z, ra.w};
        bef[2] = f2{rb.x, rb.y}; bef[3] = f2{rb.z, rb.w};
    }

    // ---------------- per-half prologue ----------------
    float tdir[2], tdif[2];
    f2 xd[2][3], xf[2][3];
#pragma unroll
    for (int h = 0; h < 2; ++h) {
        float rcp_d = __builtin_amdgcn_rcpf(MUD[h] + EPSF);
        float rcp_f = __builtin_amdgcn_rcpf(MUF[h] + EPSF);
        float tt = ((T[h][0] + T[h][1]) + (T[h][2] + T[h][3]))
                 + ((T[h][4] + T[h][5]) + (T[h][6] + T[h][7]));
        float ttl = tt * LOG2E;
        tdir[h] = ex2(-ttl * rcp_d);
        tdif[h] = ex2(-ttl * rcp_f);
        float s1 = (T[h][3] + T[h][4]) + (T[h][6] + T[h][7]);
        xd[h][0] = f2{T[h][0] * rcp_d, T[h][1] * rcp_d};
        xd[h][1] = f2{T[h][5] * rcp_d, T[h][2] * rcp_d};
        xd[h][2] = f2{s1 * rcp_d, MUD[h]};
        xf[h][0] = f2{T[h][0], T[h][1]};
        xf[h][1] = f2{T[h][5], T[h][2]};
        xf[h][2] = f2{s1, 0.0f};
    }

    // ---------------- fused 4-instance MLP (16 independent chains) ----------------
    f2 hD[2][4], hF[2][4];
#pragma unroll
    for (int p = 0; p < 4; ++p) {
        hD[0][p] = bed[p]; hD[1][p] = bed[p];
        hF[0][p] = bef[p]; hF[1][p] = bef[p];
    }
    {
        const f2* w1d = (const f2*)(ws + WD1P);
        const f2* w1f = (const f2*)(ws + WF1P);
#pragma unroll
        for (int i = 0; i < 5; ++i) {    // shared features 0..4
            f2 a0 = bc(xd[0][i >> 1], i & 1), a1 = bc(xd[1][i >> 1], i & 1);
            f2 b0v = bc(xf[0][i >> 1], i & 1), b1v = bc(xf[1][i >> 1], i & 1);
#pragma unroll
            for (int p = 0; p < 4; ++p) {
                f2 wd = w1d[i * 4 + p], wf = w1f[i * 4 + p];
                hD[0][p] = pkfma(a0, wd, hD[0][p]);
                hD[1][p] = pkfma(a1, wd, hD[1][p]);
                hF[0][p] = pkfma(b0v, wf, hF[0][p]);
                hF[1][p] = pkfma(b1v, wf, hF[1][p]);
            }
        }
        {                                 // feature 5 (mu): direct only
            f2 a0 = bc(xd[0][2], 1), a1 = bc(xd[1][2], 1);
#pragma unroll
            for (int p = 0; p < 4; ++p) {
                f2 wd = w1d[5 * 4 + p];
                hD[0][p] = pkfma(a0, wd, hD[0][p]);
                hD[1][p] = pkfma(a1, wd, hD[1][p]);
            }
        }
#pragma unroll
        for (int p = 0; p < 4; ++p) {
            hD[0][p] = pkmax0(hD[0][p]); hD[1][p] = pkmax0(hD[1][p]);
            hF[0][p] = pkmax0(hF[0][p]); hF[1][p] = pkmax0(hF[1][p]);
        }
    }
    {
        const f2* whd = (const f2*)(ws + WDHP);
        const f2* whf = (const f2*)(ws + WFHP);
        const f2* bhd = (const f2*)(ws + BDHP);
        const f2* bhf = (const f2*)(ws + BFHP);
#pragma unroll
        for (int l = 0; l < 5; ++l) {
            f2 nD[2][4], nF[2][4];
#pragma unroll
            for (int p = 0; p < 4; ++p) {
                f2 bd = bhd[l * 4 + p], bfv = bhf[l * 4 + p];
                nD[0][p] = bd;  nD[1][p] = bd;
                nF[0][p] = bfv; nF[1][p] = bfv;
            }
#pragma unroll
            for (int i = 0; i < 7; ++i) {
                f2 a0 = bc(hD[0][i >> 1], i & 1), a1 = bc(hD[1][i >> 1], i & 1);
                f2 c0 = bc(hF[0][i >> 1], i & 1), c1 = bc(hF[1][i >> 1], i & 1);
#pragma unroll
                for (int p = 0; p < 4; ++p) {
                    f2 wd = whd[(l * 7 + i) * 4 + p], wf = whf[(l * 7 + i) * 4 + p];
                    nD[0][p] = pkfma(a0, wd, nD[0][p]);
                    nD[1][p] = pkfma(a1, wd, nD[1][p]);
                    nF[0][p] = pkfma(c0, wf, nF[0][p]);
                    nF[1][p] = pkfma(c1, wf, nF[1][p]);
                }
            }
#pragma unroll
            for (int p = 0; p < 4; ++p) {
                hD[0][p] = pkmax0(nD[0][p]); hD[1][p] = pkmax0(nD[1][p]);
                hF[0][p] = pkmax0(nF[0][p]); hF[1][p] = pkmax0(nF[1][p]);
            }
        }
    }
    float od[2][3], of_[2][3];
    {
        const f2* wod = (const f2*)(ws + WDOP);
        const f2* wof = (const f2*)(ws + WFOP);
        const f2  bod = *(const f2*)(ws + BDOP);
        const f2  bof = *(const f2*)(ws + BFOP);
        float bods = ws[BDOS], bofs = ws[BFOS];
        f2 oDa[2] = {bod, bod};
        f2 oFa[2] = {bof, bof};
        float oDs[2] = {bods, bods};
        float oFs[2] = {bofs, bofs};
#pragma unroll
        for (int i = 0; i < 7; ++i) {
            f2 w0 = wod[i], v0 = wof[i];
            float wsd = ws[WDOS + i], wsf = ws[WFOS + i];
#pragma unroll
            for (int h = 0; h < 2; ++h) {
                f2 ad = bc(hD[h][i >> 1], i & 1);
                f2 af = bc(hF[h][i >> 1], i & 1);
                oDa[h] = pkfma(ad, w0, oDa[h]);
                oFa[h] = pkfma(af, v0, oFa[h]);
                oDs[h] = fmaf(half_of(hD[h][i >> 1], i & 1), wsd, oDs[h]);
                oFs[h] = fmaf(half_of(hF[h][i >> 1], i & 1), wsf, oFs[h]);
            }
        }
#pragma unroll
        for (int h = 0; h < 2; ++h) {
            od[h][0] = oDa[h].x; od[h][1] = oDa[h].y; od[h][2] = oDs[h];
            of_[h][0] = oFa[h].x; of_[h][1] = oFa[h].y; of_[h][2] = oFs[h];
        }
    }

    // ---------------- softmax (logits pre-scaled by LOG2E) ----------------
    float D0[2], D1[2], D2[2], F0[2], F1[2], F2[2];
#pragma unroll
    for (int h = 0; h < 2; ++h) {
        float md = fmaxf(fmaxf(od[h][0], od[h][1]), od[h][2]);
        float d0 = ex2(od[h][0] - md), d1 = ex2(od[h][1] - md), d2 = ex2(od[h][2] - md);
        float rdd = __builtin_amdgcn_rcpf(d0 + d1 + d2);
        D0[h] = d0 * rdd; D1[h] = d1 * rdd; D2[h] = d2 * rdd;
        float mf = fmaxf(fmaxf(of_[h][0], of_[h][1]), of_[h][2]);
        float f0 = ex2(of_[h][0] - mf), f1 = ex2(of_[h][1] - mf), f2v = ex2(of_[h][2] - mf);
        float rff = __builtin_amdgcn_rcpf(f0 + f1 + f2v);
        F0[h] = f0 * rff; F1[h] = f1 * rff; F2[h] = f2v * rff;
    }

    // ---------------- stores ----------------
    if (!is_f32 && !tail) {
#pragma unroll
        for (int h = 0; h < 2; ++h) {
            unsigned int P1 = pk_bf16(tdir[h], tdif[h]);
            unsigned int P2 = pk_bf16(D0[h], D1[h]);
            unsigned int P3 = pk_bf16(D2[h], F0[h]);
            unsigned int P4 = pk_bf16(F1[h], F2[h]);
            sm[h][tid]       = (unsigned short)P1;
            sm[h][256 + tid] = (unsigned short)(P1 >> 16);
            int db = 512 + 3 * tid;
            sm[h][db + 0] = (unsigned short)P2;
            sm[h][db + 1] = (unsigned short)(P2 >> 16);
            sm[h][db + 2] = (unsigned short)P3;
            int fb = 1280 + 3 * tid;
            sm[h][fb + 0] = (unsigned short)(P3 >> 16);
            sm[h][fb + 1] = (unsigned short)P4;
            sm[h][fb + 2] = (unsigned short)(P4 >> 16);
        }
        __syncthreads();
#pragma unroll
        for (int h = 0; h < 2; ++h) {
            uint4 v = ((const uint4*)sm[h])[tid];
            unsigned int E = (h ? (unsigned int)HBC : 0u) + (unsigned int)eb0;
            unsigned int goff;
            if (tid < 32)        goff = 2u * E + 16u * tid;
            else if (tid < 64)   goff = 2u * ((unsigned int)BC + E) + 16u * (tid - 32);
            else if (tid < 160)  goff = 4u * (unsigned int)BC + 6u * E + 16u * (tid - 64);
            else                 goff = 10u * (unsigned int)BC + 6u * E + 16u * (tid - 160);
            *(uint4*)((char*)out_p + goff) = v;
        }
    } else if (!is_f32) {
        if (act) {
            unsigned short* out = (unsigned short*)out_p;
#pragma unroll
            for (int h = 0; h < 2; ++h) {
                int e = e0 + h * HBC;
                int odb = 2 * BC + 3 * e;
                int ofb = 5 * BC + 3 * e;
                out[e]       = f2bf(tdir[h]);
                out[BC + e]  = f2bf(tdif[h]);
                out[odb + 0] = f2bf(D0[h]);
                out[odb + 1] = f2bf(D1[h]);
                out[odb + 2] = f2bf(D2[h]);
                out[ofb + 0] = f2bf(F0[h]);
                out[ofb + 1] = f2bf(F1[h]);
                out[ofb + 2] = f2bf(F2[h]);
            }
        }
    } else {
        if (act) {
            float* out = (float*)out_p;
#pragma unroll
            for (int h = 0; h < 2; ++h) {
                int e = e0 + h * HBC;
                int odb = 2 * BC + 3 * e;
                int ofb = 5 * BC + 3 * e;
                out[e] = tdir[h];
                out[BC + e] = tdif[h];
                out[odb + 0] = D0[h]; out[odb + 1] = D1[h]; out[odb + 2] = D2[h];
                out[ofb + 0] = F0[h]; out[ofb + 1] = F1[h]; out[ofb + 2] = F2[h];
            }
        }
    }
}

extern "C" void kernel_launch(void* const* d_in, const int* in_sizes, int n_in,
                              void* d_out, int out_size, void* d_ws, size_t ws_size,
                              hipStream_t stream) {
    float* ws = (float*)d_ws;
    int* flag = (int*)((char*)d_ws + FLAG_BYTE_OFF);

    P12 p;
    for (int i = 0; i < 12; ++i) p.p[i] = d_in[3 + i];
    prep<<<1, 256, 0, stream>>>(p, (const unsigned int*)d_in[0], ws, flag);

    int nblk = (HBC + 255) / 256;
    scatter_main<<<nblk, 256, 0, stream>>>(
        d_in[0], d_in[1], d_in[2], ws, flag, d_out);
}